// Round 10
// baseline (277.451 us; speedup 1.0000x reference)
//
#include <hip/hip_runtime.h>
#include <hip/hip_bf16.h>

typedef unsigned short u16;
typedef unsigned int u32;
typedef __attribute__((ext_vector_type(8))) short bf16x8;
typedef __attribute__((ext_vector_type(4))) float f32x4;

__device__ __forceinline__ u16 f2b(float f) {
    union { float f; u32 u; } v; v.f = f;
    return (u16)((v.u + 0x7FFF + ((v.u >> 16) & 1)) >> 16);  // RNE
}

__device__ __forceinline__ u32 pk2b(float a, float b) {
    union { __hip_bfloat162 h; u32 u; } v;
    v.h = __float22bfloat162_rn(make_float2(a, b));  // x=lo=a, y=hi=b
    return v.u;
}

__device__ __forceinline__ void glds16(const u16* g, u16* l) {
    __builtin_amdgcn_global_load_lds(
        (const __attribute__((address_space(1))) void*)g,
        (__attribute__((address_space(3))) void*)l, 16, 0, 0);
}

// ---------------------------------------------------------------------------
// fp32 -> bf16 flat casts for Q, K, V (grid.z selects input). n4 = 1048576.
// ---------------------------------------------------------------------------
__global__ __launch_bounds__(256) void cast3(
    const float* __restrict__ Q, const float* __restrict__ K,
    const float* __restrict__ V,
    u16* __restrict__ Qb, u16* __restrict__ Kb, u16* __restrict__ Vb)
{
    const float* in = (blockIdx.z == 0) ? Q : (blockIdx.z == 1) ? K : V;
    u16* out = (blockIdx.z == 0) ? Qb : (blockIdx.z == 1) ? Kb : Vb;
    const int n4 = 1048576;
    const int stride = gridDim.x * 256;
    for (int i = blockIdx.x * 256 + threadIdx.x; i < n4; i += stride) {
        float4 v = ((const float4*)in)[i];
        ushort4 o;
        o.x = f2b(v.x); o.y = f2b(v.y); o.z = f2b(v.z); o.w = f2b(v.w);
        ((ushort4*)out)[i] = o;
    }
}

// ---------------------------------------------------------------------------
// Per-head weight transpose-cast: fp32 [16][1024][64] -> bf16 [16][64][1024].
// grid (16, 1, 48): z>>4 selects Wq/Wk/Wv, z&15 = head.
// ---------------------------------------------------------------------------
__global__ __launch_bounds__(256) void tcastW(
    const float* __restrict__ Wq, const float* __restrict__ Wk,
    const float* __restrict__ Wv,
    u16* __restrict__ WqT, u16* __restrict__ WkT, u16* __restrict__ WvT)
{
    __shared__ float t[64][68];
    const int sel = blockIdx.z >> 4, hz = blockIdx.z & 15;
    const float* in = (sel == 0) ? Wq : (sel == 1) ? Wk : Wv;
    u16* out = (sel == 0) ? WqT : (sel == 1) ? WkT : WvT;
    const long mb = (long)hz * 65536;
    const int r0 = blockIdx.x * 64;
    const int tid = threadIdx.x;
    const int rr = tid >> 4, c4 = (tid & 15) * 4;

    #pragma unroll
    for (int p = 0; p < 4; ++p) {
        float4 v = *(const float4*)(in + mb + (long)(r0 + p * 16 + rr) * 64 + c4);
        *(float4*)&t[p * 16 + rr][c4] = v;
    }
    __syncthreads();
    #pragma unroll
    for (int p = 0; p < 4; ++p) {
        const int oc = p * 16 + rr;          // output row (col of W, 0..63)
        const int r4 = (tid & 15) * 4;
        ushort4 o;
        o.x = f2b(t[r4 + 0][oc]); o.y = f2b(t[r4 + 1][oc]);
        o.z = f2b(t[r4 + 2][oc]); o.w = f2b(t[r4 + 3][oc]);
        *(ushort4*)(out + mb + (long)oc * 1024 + r0 + r4) = o;
    }
}

// ---------------------------------------------------------------------------
// Wo transpose-cast: fp32 [1024][1024] -> bf16 [1024][1024]^T. grid (16,16).
// ---------------------------------------------------------------------------
__global__ __launch_bounds__(256) void tcastWo(
    const float* __restrict__ in, u16* __restrict__ out)
{
    __shared__ float t[64][68];
    const int r0 = blockIdx.x * 64, c0 = blockIdx.y * 64;
    const int tid = threadIdx.x;
    const int rr = tid >> 4, c4 = (tid & 15) * 4;

    #pragma unroll
    for (int p = 0; p < 4; ++p) {
        float4 v = *(const float4*)(in + (long)(r0 + p * 16 + rr) * 1024 + c0 + c4);
        *(float4*)&t[p * 16 + rr][c4] = v;
    }
    __syncthreads();
    #pragma unroll
    for (int p = 0; p < 4; ++p) {
        const int oc = p * 16 + rr;
        const int r4 = (tid & 15) * 4;
        ushort4 o;
        o.x = f2b(t[r4 + 0][oc]); o.y = f2b(t[r4 + 1][oc]);
        o.z = f2b(t[r4 + 2][oc]); o.w = f2b(t[r4 + 3][oc]);
        *(ushort4*)(out + (long)(c0 + oc) * 1024 + r0 + r4) = o;
    }
}

// ---------------------------------------------------------------------------
// GEMM body macro shared by proj3 / gemm_out.
// 128x128 tile, 4 waves 2x2, XOR-swizzled LDS (chunk stored at chunk^(row&7)).
// ---------------------------------------------------------------------------
#define GEMM_CORE(A_, BT_)                                                     \
    __shared__ u16 As[128 * 64];                                               \
    __shared__ u16 Bs[128 * 64];                                               \
    const int tid = threadIdx.x, lane = tid & 63, w = tid >> 6;                \
    const int m0 = blockIdx.y * 128, n0 = blockIdx.x * 128;                    \
    const int wm = (w >> 1) * 64, wn = (w & 1) * 64;                           \
    const int fr = lane & 15, quad = lane >> 4;                                \
    f32x4 acc[4][4];                                                           \
    const f32x4 zero = {0.f, 0.f, 0.f, 0.f};                                   \
    _Pragma("unroll")                                                          \
    for (int mi = 0; mi < 4; ++mi)                                             \
        _Pragma("unroll")                                                      \
        for (int ni = 0; ni < 4; ++ni) acc[mi][ni] = zero;                     \
    const int srow = lane >> 3;                                                \
    const int schk = (lane & 7) ^ (srow & 7);   /* swizzled source chunk */    \
    const long ga = (long)(m0 + srow) * 1024 + schk * 8;                       \
    const long gb = (long)(n0 + srow) * 1024 + schk * 8;                       \
    const int f7 = fr & 7;                                                     \
    for (int k0 = 0; k0 < 1024; k0 += 64) {                                    \
        __syncthreads();                                                       \
        _Pragma("unroll")                                                      \
        for (int i2 = 0; i2 < 4; ++i2) {                                       \
            const int i = w * 4 + i2;                                          \
            glds16(A_ + ga + (long)i * 8 * 1024 + k0, &As[i * 512]);           \
            glds16(BT_ + gb + (long)i * 8 * 1024 + k0, &Bs[i * 512]);          \
        }                                                                      \
        __syncthreads();                                                       \
        _Pragma("unroll")                                                      \
        for (int kc = 0; kc < 2; ++kc) {                                       \
            const int pos = ((kc * 4 + quad) ^ f7) * 8;                        \
            bf16x8 af[4], bfr[4];                                              \
            _Pragma("unroll")                                                  \
            for (int mi = 0; mi < 4; ++mi)                                     \
                af[mi] = *(const bf16x8*)&As[(wm + mi * 16 + fr) * 64 + pos];  \
            _Pragma("unroll")                                                  \
            for (int ni = 0; ni < 4; ++ni)                                     \
                bfr[ni] = *(const bf16x8*)&Bs[(wn + ni * 16 + fr) * 64 + pos]; \
            _Pragma("unroll")                                                  \
            for (int mi = 0; mi < 4; ++mi)                                     \
                _Pragma("unroll")                                              \
                for (int ni = 0; ni < 4; ++ni)                                 \
                    acc[mi][ni] = __builtin_amdgcn_mfma_f32_16x16x32_bf16(     \
                        af[mi], bfr[ni], acc[mi][ni], 0, 0, 0);                \
        }                                                                      \
    }

// Projections (z: 0=Q, 1=K, 2=V). OUT: z<2 -> [bh][s][64]; z==2 -> [bh][64][s]
// Q output is pre-scaled by log2(e) so attention can use exp2.
__global__ __launch_bounds__(256) void proj3(
    const u16* __restrict__ Qb, const u16* __restrict__ Kb,
    const u16* __restrict__ Vb,
    const u16* __restrict__ WqT, const u16* __restrict__ WkT,
    const u16* __restrict__ WvT,
    const float* __restrict__ bq, const float* __restrict__ bk,
    const float* __restrict__ bv,
    u16* __restrict__ QWb, u16* __restrict__ KWb, u16* __restrict__ VWb)
{
    const int z = blockIdx.z;
    const u16* A  = (z == 0) ? Qb : (z == 1) ? Kb : Vb;
    const u16* BT = (z == 0) ? WqT : (z == 1) ? WkT : WvT;
    const float* bias = (z == 0) ? bq : (z == 1) ? bk : bv;
    u16* Cu = (z == 0) ? QWb : (z == 1) ? KWb : VWb;
    const float scl = (z == 0) ? 1.44269504f : 1.0f;

    GEMM_CORE(A, BT)

    #pragma unroll
    for (int mi = 0; mi < 4; ++mi) {
        #pragma unroll
        for (int ni = 0; ni < 4; ++ni) {
            #pragma unroll
            for (int r = 0; r < 4; ++r) {
                const int m = m0 + wm + mi * 16 + quad * 4 + r;
                const int c = n0 + wn + ni * 16 + fr;
                const float v = (acc[mi][ni][r] + bias[c]) * scl;
                const int b = m >> 11, s = m & 2047, h = c >> 6, k = c & 63;
                if (z != 2)
                    Cu[((long)(b * 16 + h) * 2048 + s) * 64 + k] = f2b(v);
                else
                    Cu[((long)(b * 16 + h) * 64 + k) * 2048 + s] = f2b(v);
            }
        }
    }
}

// Output projection: fp32 out = ctx(bf16) @ WoT^T + bo
__global__ __launch_bounds__(256) void gemm_out(
    const u16* __restrict__ A, const u16* __restrict__ BT,
    const float* __restrict__ bias, float* __restrict__ Cf)
{
    GEMM_CORE(A, BT)

    #pragma unroll
    for (int mi = 0; mi < 4; ++mi) {
        #pragma unroll
        for (int ni = 0; ni < 4; ++ni) {
            #pragma unroll
            for (int r = 0; r < 4; ++r) {
                const int m = m0 + wm + mi * 16 + quad * 4 + r;
                const int c = n0 + wn + ni * 16 + fr;
                Cf[(long)m * 1024 + c] = acc[mi][ni][r] + bias[c];
            }
        }
    }
}

// ---------------------------------------------------------------------------
// MFMA flash attention v3. QW (pre-scaled by log2e)/KW: [bh][2048][64];
// VW: [bh][64][2048] (bf16). Block = 4 waves, 128 q rows (2 sets of 16/wave).
// Non-centered softmax via exp2; l accumulated by ones-MFMA.
// K/V B-frags hoisted to registers and reused across both q-sets.
// ---------------------------------------------------------------------------
__global__ __launch_bounds__(256) void attn_mfma(
    const u16* __restrict__ QW, const u16* __restrict__ KW,
    const u16* __restrict__ VW, u16* __restrict__ ctxb)
{
    __shared__ u16 kt[64 * 64];      // [t][k] swizzled, 8 KB
    __shared__ u16 vt[64 * 64];      // [d][t] swizzled, 8 KB
    __shared__ u16 ps[4][32 * 72];   // per-wave P [q][t], stride 72, 18 KB

    const int tid = threadIdx.x, lane = tid & 63, w = tid >> 6;
    const int bh = blockIdx.y, b = bh >> 4, h = bh & 15;
    const int q0 = blockIdx.x * 128;
    const int fr = lane & 15, quad = lane >> 4;
    const int f7 = fr & 7;

    // Q A-frags: 2 q-sets of 16 rows
    bf16x8 aQ[2][2];
    #pragma unroll
    for (int s = 0; s < 2; ++s) {
        const u16* qp = QW + ((long)bh * 2048 + q0 + w * 32 + s * 16 + fr) * 64;
        aQ[s][0] = *(const bf16x8*)(qp + quad * 8);
        aQ[s][1] = *(const bf16x8*)(qp + 32 + quad * 8);
    }

    const f32x4 zero = {0.f, 0.f, 0.f, 0.f};
    f32x4 acc[2][4], lac[2];
    #pragma unroll
    for (int s = 0; s < 2; ++s) {
        lac[s] = zero;
        #pragma unroll
        for (int d = 0; d < 4; ++d) acc[s][d] = zero;
    }
    bf16x8 bones;
    #pragma unroll
    for (int j = 0; j < 8; ++j) bones[j] = (short)0x3F80;  // bf16 1.0

    const int srow = lane >> 3;
    const int schk = (lane & 7) ^ (srow & 7);   // swizzled source chunk
    const long kgb = (long)bh * (2048 * 64);
    const long vgb = (long)bh * (64 * 2048);

    for (int t0 = 0; t0 < 2048; t0 += 64) {
        __syncthreads();
        #pragma unroll
        for (int i2 = 0; i2 < 2; ++i2) {
            const int i = w * 2 + i2;
            glds16(KW + kgb + (long)(t0 + i * 8 + srow) * 64 + schk * 8, &kt[i * 512]);
            glds16(VW + vgb + (long)(i * 8 + srow) * 2048 + t0 + schk * 8, &vt[i * 512]);
        }
        __syncthreads();

        const int pos0 = (quad ^ f7) * 8;      // swizzled chunk {quad}
        const int pos1 = pos0 ^ 32;            // swizzled chunk {quad+4}

        // ---- hoisted K B-frags (shared across both q-sets) ----
        bf16x8 kb0[4], kb1[4];
        #pragma unroll
        for (int sub = 0; sub < 4; ++sub) {
            const int row = (sub * 16 + fr) * 64;
            kb0[sub] = *(const bf16x8*)&kt[row + pos0];
            kb1[sub] = *(const bf16x8*)&kt[row + pos1];
        }
        // ---- QK^T both sets ----
        f32x4 sc[2][4];
        #pragma unroll
        for (int s = 0; s < 2; ++s)
            #pragma unroll
            for (int sub = 0; sub < 4; ++sub) {
                f32x4 z = __builtin_amdgcn_mfma_f32_16x16x32_bf16(aQ[s][0], kb0[sub], zero, 0, 0, 0);
                sc[s][sub] = __builtin_amdgcn_mfma_f32_16x16x32_bf16(aQ[s][1], kb1[sub], z, 0, 0, 0);
            }
        // ---- exp2 + packed-cvt P store ----
        #pragma unroll
        for (int s = 0; s < 2; ++s) {
            u16* pw = ps[w] + s * 16 * 72;
            #pragma unroll
            for (int sub = 0; sub < 4; ++sub) {
                #pragma unroll
                for (int rp = 0; rp < 2; ++rp) {
                    const u32 u = pk2b(exp2f(sc[s][sub][rp * 2]),
                                       exp2f(sc[s][sub][rp * 2 + 1]));
                    const int base = (quad * 4 + rp * 2) * 72 + sub * 16 + fr;
                    pw[base]      = (u16)(u & 0xffff);
                    pw[base + 72] = (u16)(u >> 16);
                }
            }
        }
        __asm__ volatile("s_waitcnt lgkmcnt(0)" ::: "memory");

        // ---- hoisted V B-frags (shared across both q-sets) ----
        bf16x8 vb0[4], vb1[4];
        #pragma unroll
        for (int d = 0; d < 4; ++d) {
            const int row = (d * 16 + fr) * 64;
            vb0[d] = *(const bf16x8*)&vt[row + pos0];
            vb1[d] = *(const bf16x8*)&vt[row + pos1];
        }
        // ---- l (ones-MFMA) + PV both sets ----
        #pragma unroll
        for (int s = 0; s < 2; ++s) {
            const u16* pw = ps[w] + s * 16 * 72;
            const bf16x8 aP0 = *(const bf16x8*)&pw[fr * 72 + quad * 8];
            const bf16x8 aP1 = *(const bf16x8*)&pw[fr * 72 + 32 + quad * 8];
            lac[s] = __builtin_amdgcn_mfma_f32_16x16x32_bf16(aP0, bones, lac[s], 0, 0, 0);
            lac[s] = __builtin_amdgcn_mfma_f32_16x16x32_bf16(aP1, bones, lac[s], 0, 0, 0);
            #pragma unroll
            for (int d = 0; d < 4; ++d) {
                acc[s][d] = __builtin_amdgcn_mfma_f32_16x16x32_bf16(aP0, vb0[d], acc[s][d], 0, 0, 0);
                acc[s][d] = __builtin_amdgcn_mfma_f32_16x16x32_bf16(aP1, vb1[d], acc[s][d], 0, 0, 0);
            }
        }
    }

    // epilogue: ctx = acc/(l*128), row = q0 + w*32 + s*16 + quad*4 + r
    #pragma unroll
    for (int s = 0; s < 2; ++s) {
        #pragma unroll
        for (int r = 0; r < 4; ++r) {
            const float scl = 1.0f / (lac[s][r] * 128.0f);
            const long row = (long)b * 2048 + q0 + w * 32 + s * 16 + quad * 4 + r;
            #pragma unroll
            for (int d = 0; d < 4; ++d)
                ctxb[row * 1024 + h * 64 + d * 16 + fr] = f2b(acc[s][d][r] * scl);
        }
    }
}

// ---------------------------------------------------------------------------
extern "C" void kernel_launch(void* const* d_in, const int* in_sizes, int n_in,
                              void* d_out, int out_size, void* d_ws, size_t ws_size,
                              hipStream_t stream) {
    (void)in_sizes; (void)n_in; (void)out_size; (void)ws_size;

    const float* Q  = (const float*)d_in[0];
    const float* K  = (const float*)d_in[1];
    const float* V  = (const float*)d_in[2];
    const float* Wq = (const float*)d_in[3];
    const float* bq = (const float*)d_in[4];
    const float* Wk = (const float*)d_in[5];
    const float* bk = (const float*)d_in[6];
    const float* Wv = (const float*)d_in[7];
    const float* bv = (const float*)d_in[8];
    const float* Wo = (const float*)d_in[9];
    const float* bo = (const float*)d_in[10];
    float* out = (float*)d_out;

    u16* ws  = (u16*)d_ws;                // 67 MB total (proven safe)
    u16* Qb  = ws;                        // 4096x1024
    u16* Kb  = Qb  + 4194304;
    u16* Vb  = Kb  + 4194304;
    u16* WqT = Vb  + 4194304;             // [16][64][1024]
    u16* WkT = WqT + 1048576;
    u16* WvT = WkT + 1048576;
    u16* WoT = WvT + 1048576;             // [1024][1024]
    u16* QWb = WoT + 1048576;             // [32][2048][64]
    u16* KWb = QWb + 4194304;             // [32][2048][64]
    u16* VWb = KWb + 4194304;             // [32][64][2048]
    u16* ctx = VWb + 4194304;             // [4096][1024]

    cast3<<<dim3(1024, 1, 3), 256, 0, stream>>>(Q, K, V, Qb, Kb, Vb);
    tcastW<<<dim3(16, 1, 48), 256, 0, stream>>>(Wq, Wk, Wv, WqT, WkT, WvT);
    tcastWo<<<dim3(16, 16), 256, 0, stream>>>(Wo, WoT);

    proj3<<<dim3(8, 32, 3), 256, 0, stream>>>(Qb, Kb, Vb, WqT, WkT, WvT,
                                              bq, bk, bv, QWb, KWb, VWb);

    attn_mfma<<<dim3(16, 32), 256, 0, stream>>>(QWb, KWb, VWb, ctx);

    gemm_out<<<dim3(8, 32), 256, 0, stream>>>(ctx, WoT, bo, out);
}